// Round 1
// baseline (48077.277 us; speedup 1.0000x reference)
//
#include <hip/hip_runtime.h>
#include <math.h>

// ---------------- problem constants ----------------
constexpr int MM = 8;      // batch of GPs
constexpr int NC = 1024;   // context points
constexpr int NT = 512;    // target points
// DX = 3
// Workspace layout (floats):
//  Kb   : MM*1024*1024   (K -> L -> G = K^-1)
//  Ab   : MM*1024*1024   (diag-block inverses + A = L^-1; reused as W at predict)
//  Tb   : MM*512*512     (trinv temp)
//  Ktc  : MM*NT*NC
//  alpha: MM*1024
//  scal : MM*32  per-m: [0..3] raw params(ls,os,noise,const) [4..7] adam m
//                       [8..11] adam v [12]ls [13]os [14]noise [15]T1 [16]T2
constexpr size_t OFF_A     = (size_t)MM * 1024 * 1024;
constexpr size_t OFF_T     = OFF_A * 2;
constexpr size_t OFF_KTC   = OFF_T + (size_t)MM * 512 * 512;
constexpr size_t OFF_ALPHA = OFF_KTC + (size_t)MM * NT * NC;
constexpr size_t OFF_SCAL  = OFF_ALPHA + (size_t)MM * 1024;

#define S5 2.2360679775f

__device__ __forceinline__ float sigmf(float x) { return 1.0f / (1.0f + expf(-x)); }
__device__ __forceinline__ float softplusf(float x) { return fmaxf(x, 0.0f) + log1pf(expf(-fabsf(x))); }

__device__ __forceinline__ void lt_decode(int x, int& i, int& j) {
  int ii = 0;
  while ((ii + 1) * (ii + 2) / 2 <= x) ++ii;
  i = ii; j = x - ii * (ii + 1) / 2;
}

// ---------------- init ----------------
__global__ void k_init(float* scal) {
  int t = threadIdx.x;
  if (t < MM) {
    float* s = scal + t * 32;
    for (int i = 0; i < 12; ++i) s[i] = 0.0f;
    float sp0 = 0.69314718056f;  // softplus(0)
    s[12] = sp0; s[13] = sp0; s[14] = sp0 + 1e-4f;
    s[15] = 0.0f; s[16] = 0.0f;
  }
}

// ---------------- build K (lower tiles) ----------------
__global__ __launch_bounds__(256) void k_buildK(const float* __restrict__ xc,
                                                float* __restrict__ Kb,
                                                const float* __restrict__ scal, int n) {
  int m = blockIdx.y, tid = threadIdx.x;
  int bi, bj; lt_decode(blockIdx.x, bi, bj);
  __shared__ float xi[128][3], xj[128][3];
  const float* xm = xc + (size_t)m * NC * 3;
  const float* s = scal + m * 32;
  float ls = s[12], os = s[13], noi = s[14];
  float il2 = 1.0f / (ls * ls);
  if (tid < 128) {
    int r = bi * 128 + tid;
    xi[tid][0] = xm[r*3+0]; xi[tid][1] = xm[r*3+1]; xi[tid][2] = xm[r*3+2];
  } else {
    int lr = tid - 128; int r = bj * 128 + lr;
    xj[lr][0] = xm[r*3+0]; xj[lr][1] = xm[r*3+1]; xj[lr][2] = xm[r*3+2];
  }
  __syncthreads();
  float* Km = Kb + (size_t)m * 1048576;
  for (int e = tid; e < 16384; e += 256) {
    int r = e >> 7, c = e & 127;
    float d0 = xi[r][0]-xj[c][0], d1 = xi[r][1]-xj[c][1], d2 = xi[r][2]-xj[c][2];
    float r2 = d0*d0 + d1*d1 + d2*d2;
    float z = fmaxf(r2 * il2, 1e-12f);
    float dd = sqrtf(z);
    float kv = os * (1.0f + S5*dd + (5.0f/3.0f)*z) * expf(-S5*dd);
    int gr = bi*128 + r, gc = bj*128 + c;
    if (gr == gc) kv += noi;
    Km[(size_t)gr * n + gc] = kv;
  }
}

// ---------------- diag block: factor 128x128 + invert -> Ab[k,k] ----------------
__global__ __launch_bounds__(256) void k_chol_diag(float* __restrict__ Kb,
                                                   float* __restrict__ Ab, int k, int n) {
  __shared__ float Ls[128 * 129];
  __shared__ float Us[128 * 129];
  __shared__ float Tt[64 * 65];
  int m = blockIdx.x, tid = threadIdx.x;
  float* Km = Kb + (size_t)m * 1048576 + (size_t)(k * 128) * n + k * 128;
  float* Am = Ab + (size_t)m * 1048576 + (size_t)(k * 128) * n + k * 128;
  for (int e = tid; e < 16384; e += 256) { int r = e >> 7, c = e & 127; Ls[r*129+c] = Km[(size_t)r*n + c]; }
  __syncthreads();
  int tx = tid & 15, ty = tid >> 4;
  for (int j = 0; j < 128; ++j) {
    if (tid == 0) Ls[j*129+j] = sqrtf(Ls[j*129+j]);
    __syncthreads();
    float dinv = 1.0f / Ls[j*129+j];
    for (int i = j + 1 + tid; i < 128; i += 256) Ls[i*129+j] *= dinv;
    __syncthreads();
    for (int i = j + 1 + ty; i < 128; i += 16) {
      float lij = Ls[i*129+j];
      for (int c = j + 1 + tx; c <= i; c += 16) Ls[i*129+c] -= lij * Ls[c*129+j];
    }
    __syncthreads();
  }
  for (int e = tid; e < 128 * 129; e += 256) Us[e] = 0.0f;
  __syncthreads();
  // invert four 32x32 diagonal sub-blocks (thread-per-column)
  if (tid < 128) {
    int b = tid >> 5, c0 = tid & 31, base = b * 32, gc = base + c0;
    Us[gc*129+gc] = 1.0f / Ls[gc*129+gc];
    for (int r = c0 + 1; r < 32; ++r) {
      int gr = base + r;
      float acc = 0.0f;
      for (int l = c0; l < r; ++l) acc += Ls[gr*129 + base + l] * Us[(base+l)*129 + gc];
      Us[gr*129+gc] = -acc / Ls[gr*129+gr];
    }
  }
  __syncthreads();
  // assemble 32 -> 64 -> 128 : U21 = -U22 * (L21 * U11)
#pragma unroll
  for (int s = 32; s < 128; s <<= 1) {
    int npairs = 128 / (2 * s);
    int total = npairs * s * s;
    for (int e = tid; e < total; e += 256) {
      int p = e / (s * s); int rem = e - p * s * s; int r = rem / s; int c = rem - r * s;
      int rb = 2*p*s + s, cb = 2*p*s;
      float acc = 0.0f;
      for (int l = c; l < s; ++l) acc += Ls[(rb+r)*129 + cb + l] * Us[(cb+l)*129 + cb + c];
      Tt[p*s*(s+1) + r*(s+1) + c] = acc;
    }
    __syncthreads();
    for (int e = tid; e < total; e += 256) {
      int p = e / (s * s); int rem = e - p * s * s; int r = rem / s; int c = rem - r * s;
      int rb = 2*p*s + s, cb = 2*p*s;
      float acc = 0.0f;
      for (int l = 0; l <= r; ++l) acc += Us[(rb+r)*129 + rb + l] * Tt[p*s*(s+1) + l*(s+1) + c];
      Us[(rb+r)*129 + cb + c] = -acc;
    }
    __syncthreads();
  }
  for (int e = tid; e < 16384; e += 256) { int r = e >> 7, c = e & 127; Am[(size_t)r*n + c] = Us[r*129+c]; }
}

// ---------------- shared 128x128 GEMM core ----------------
// logical A(r,k): TA ? A[k*lda+r] : A[r*lda+k];  logical B(k,c): TB ? B[c*ldb+k] : B[k*ldb+c]
template <int TA, int TB>
__device__ __forceinline__ void mm_core(const float* __restrict__ A, int lda,
                                        const float* __restrict__ B, int ldb,
                                        int kBeg, int kEnd, float acc[8][8]) {
  __shared__ float As[8][132];
  __shared__ float Bs[8][132];
  int tid = threadIdx.x, tx = tid & 15, ty = tid >> 4;
  for (int k0 = kBeg; k0 < kEnd; k0 += 8) {
    __syncthreads();
    if (TA) {
      for (int e = tid; e < 1024; e += 256) { int kk = e >> 7, r = e & 127; As[kk][r] = A[(size_t)(k0+kk)*lda + r]; }
    } else {
      for (int e = tid; e < 1024; e += 256) { int r = e >> 3, kk = e & 7; As[kk][r] = A[(size_t)r*lda + (k0+kk)]; }
    }
    if (TB) {
      for (int e = tid; e < 1024; e += 256) { int c = e >> 3, kk = e & 7; Bs[kk][c] = B[(size_t)c*ldb + (k0+kk)]; }
    } else {
      for (int e = tid; e < 1024; e += 256) { int kk = e >> 7, c = e & 127; Bs[kk][c] = B[(size_t)(k0+kk)*ldb + c]; }
    }
    __syncthreads();
#pragma unroll
    for (int kk = 0; kk < 8; ++kk) {
      float a[8], b[8];
#pragma unroll
      for (int i = 0; i < 8; ++i) a[i] = As[kk][ty*8+i];
#pragma unroll
      for (int j = 0; j < 8; ++j) b[j] = Bs[kk][tx*8+j];
#pragma unroll
      for (int i = 0; i < 8; ++i)
#pragma unroll
        for (int j = 0; j < 8; ++j) acc[i][j] = fmaf(a[i], b[j], acc[i][j]);
    }
  }
}

// panel: L[i,k] = K[i,k] * Linv[k,k]^T  (in place over K[i,k])
__global__ __launch_bounds__(256) void k_panel(float* __restrict__ Kb, const float* __restrict__ Ab,
                                               int k, int n) {
  int m = blockIdx.y, i = k + 1 + blockIdx.x;
  float* Km = Kb + (size_t)m * 1048576;
  const float* Am = Ab + (size_t)m * 1048576;
  float acc[8][8] = {};
  const float* A = Km + (size_t)(i*128)*n + k*128;
  const float* B = Am + (size_t)(k*128)*n + k*128;  // Linv (lower); use as B^T
  mm_core<0, 1>(A, n, B, n, 0, 128, acc);
  float* C = Km + (size_t)(i*128)*n + k*128;
  int tx = threadIdx.x & 15, ty = threadIdx.x >> 4;
#pragma unroll
  for (int ii = 0; ii < 8; ++ii)
#pragma unroll
    for (int jj = 0; jj < 8; ++jj) C[(size_t)(ty*8+ii)*n + tx*8+jj] = acc[ii][jj];
}

// trailing: K[i,j] -= L[i,k] * L[j,k]^T
__global__ __launch_bounds__(256) void k_trail(float* __restrict__ Kb, int k, int n) {
  int m = blockIdx.y;
  int di, dj; lt_decode(blockIdx.x, di, dj);
  int i = k + 1 + di, j = k + 1 + dj;
  float* Km = Kb + (size_t)m * 1048576;
  float acc[8][8] = {};
  const float* A = Km + (size_t)(i*128)*n + k*128;
  const float* B = Km + (size_t)(j*128)*n + k*128;
  mm_core<0, 1>(A, n, B, n, 0, 128, acc);
  float* C = Km + (size_t)(i*128)*n + j*128;
  int tx = threadIdx.x & 15, ty = threadIdx.x >> 4;
#pragma unroll
  for (int ii = 0; ii < 8; ++ii)
#pragma unroll
    for (int jj = 0; jj < 8; ++jj) C[(size_t)(ty*8+ii)*n + tx*8+jj] -= acc[ii][jj];
}

// trinv phase 1: T = L21 * A11 (A11 block-lower)
__global__ __launch_bounds__(256) void k_trinvT(const float* __restrict__ Kb, const float* __restrict__ Ab,
                                                float* __restrict__ Tb, int s, int n) {
  int m = blockIdx.y, st = s >> 7;
  int p = blockIdx.x / (st * st), rem = blockIdx.x % (st * st);
  int ti = rem / st, tj = rem % st;
  int base = p * 2 * s;
  const float* Km = Kb + (size_t)m * 1048576;
  const float* Am = Ab + (size_t)m * 1048576;
  float acc[8][8] = {};
  const float* A = Km + (size_t)(base + s + ti*128) * n + base;        // L21 rows
  const float* B = Am + (size_t)base * n + base + tj*128;              // A11
  mm_core<0, 0>(A, n, B, n, tj * 128, s, acc);
  float* C = Tb + (size_t)m * 262144 + (size_t)p * s * s + (size_t)(ti*128) * s + tj*128;
  int tx = threadIdx.x & 15, ty = threadIdx.x >> 4;
#pragma unroll
  for (int ii = 0; ii < 8; ++ii)
#pragma unroll
    for (int jj = 0; jj < 8; ++jj) C[(size_t)(ty*8+ii)*s + tx*8+jj] = acc[ii][jj];
}

// trinv phase 2: A21 = -A22 * T (A22 block-lower)
__global__ __launch_bounds__(256) void k_trinvA(float* __restrict__ Ab, const float* __restrict__ Tb,
                                                int s, int n) {
  int m = blockIdx.y, st = s >> 7;
  int p = blockIdx.x / (st * st), rem = blockIdx.x % (st * st);
  int ti = rem / st, tj = rem % st;
  int base = p * 2 * s;
  float* Am = Ab + (size_t)m * 1048576;
  float acc[8][8] = {};
  const float* A = Am + (size_t)(base + s + ti*128) * n + base + s;    // A22
  const float* B = Tb + (size_t)m * 262144 + (size_t)p * s * s + tj*128;
  mm_core<0, 0>(A, n, B, s, 0, (ti + 1) * 128, acc);
  float* C = Am + (size_t)(base + s + ti*128) * n + base + tj*128;
  int tx = threadIdx.x & 15, ty = threadIdx.x >> 4;
#pragma unroll
  for (int ii = 0; ii < 8; ++ii)
#pragma unroll
    for (int jj = 0; jj < 8; ++jj) C[(size_t)(ty*8+ii)*n + tx*8+jj] = -acc[ii][jj];
}

// syrk: G = A^T A (A lower-tri), write lower tile + mirror
__global__ __launch_bounds__(256) void k_syrk(const float* __restrict__ Ab, float* __restrict__ Kb, int n) {
  int m = blockIdx.y;
  int ib, jb; lt_decode(blockIdx.x, ib, jb);
  const float* Am = Ab + (size_t)m * 1048576;
  float* Gm = Kb + (size_t)m * 1048576;
  float acc[8][8] = {};
  const float* A = Am + ib * 128;   // A(k, ib*128+r) = A[k*n + ib*128+r]
  const float* B = Am + jb * 128;
  mm_core<1, 0>(A, n, B, n, ib * 128, n, acc);
  int tx = threadIdx.x & 15, ty = threadIdx.x >> 4;
#pragma unroll
  for (int ii = 0; ii < 8; ++ii)
#pragma unroll
    for (int jj = 0; jj < 8; ++jj) {
      int r = ty*8+ii, c = tx*8+jj;
      Gm[(size_t)(ib*128+r)*n + jb*128+c] = acc[ii][jj];
      if (ib != jb) Gm[(size_t)(jb*128+c)*n + ib*128+r] = acc[ii][jj];
    }
}

// alpha = G * (y - const); also zero T1/T2 accumulators
__global__ __launch_bounds__(256) void k_alpha(const float* __restrict__ Kb, const float* __restrict__ yc,
                                               float* __restrict__ scal, float* __restrict__ alpha, int n) {
  int m = blockIdx.y, tid = threadIdx.x;
  int i = blockIdx.x * 256 + tid;
  const float* G = Kb + (size_t)m * 1048576;
  const float* y = yc + (size_t)m * NC;
  float cm = scal[m*32 + 3];
  float acc = 0.0f;
#pragma unroll 4
  for (int j = 0; j < n; ++j) acc = fmaf(G[(size_t)j*n + i], y[j] - cm, acc);
  alpha[m*1024 + i] = acc;
  if (blockIdx.x == 0 && tid < 2) scal[m*32 + 15 + tid] = 0.0f;
}

// reduce: T1 = sum G.*C, T2 = alpha^T C alpha  (C recomputed on the fly)
__global__ __launch_bounds__(256) void k_reduce(const float* __restrict__ Kb, const float* __restrict__ xc,
                                                const float* __restrict__ alpha, float* __restrict__ scal, int n) {
  int m = blockIdx.y, tid = threadIdx.x;
  int nb = n >> 7;
  int bi = blockIdx.x / nb, bj = blockIdx.x % nb;
  __shared__ float xi[128][3], xj[128][3], ai[128], aj[128];
  const float* xm = xc + (size_t)m * NC * 3;
  const float* s = scal + m * 32;
  float ls = s[12], os = s[13];
  float il2 = 1.0f / (ls * ls);
  float c53 = (5.0f / 3.0f) * os / ls;
  if (tid < 128) {
    int r = bi * 128 + tid;
    xi[tid][0]=xm[r*3+0]; xi[tid][1]=xm[r*3+1]; xi[tid][2]=xm[r*3+2];
    ai[tid] = alpha[m*1024 + r];
  } else {
    int lr = tid - 128; int r = bj * 128 + lr;
    xj[lr][0]=xm[r*3+0]; xj[lr][1]=xm[r*3+1]; xj[lr][2]=xm[r*3+2];
    aj[lr] = alpha[m*1024 + r];
  }
  __syncthreads();
  const float* G = Kb + (size_t)m * 1048576;
  float a1 = 0.0f, a2 = 0.0f;
  for (int e = tid; e < 16384; e += 256) {
    int r = e >> 7, c = e & 127;
    float d0 = xi[r][0]-xj[c][0], d1 = xi[r][1]-xj[c][1], d2 = xi[r][2]-xj[c][2];
    float r2 = d0*d0 + d1*d1 + d2*d2;
    float z = fmaxf(r2 * il2, 1e-12f);
    float dd = sqrtf(z);
    float Cv = c53 * z * (1.0f + S5*dd) * expf(-S5*dd);
    float g = G[(size_t)(bi*128+r)*n + bj*128 + c];
    a1 = fmaf(g, Cv, a1);
    a2 = fmaf(ai[r]*aj[c], Cv, a2);
  }
  // block reduce
  for (int off = 32; off; off >>= 1) { a1 += __shfl_down(a1, off); a2 += __shfl_down(a2, off); }
  __shared__ float red[4][2];
  int wid = tid >> 6, lane = tid & 63;
  if (lane == 0) { red[wid][0] = a1; red[wid][1] = a2; }
  __syncthreads();
  if (tid == 0) {
    a1 = red[0][0]+red[1][0]+red[2][0]+red[3][0];
    a2 = red[0][1]+red[1][1]+red[2][1]+red[3][1];
    atomicAdd(&scal[m*32 + 15], a1);
    atomicAdd(&scal[m*32 + 16], a2);
  }
}

// adam: finish reductions (trG, |a|^2, sum a, diff.a), compute grads, update params
__global__ __launch_bounds__(256) void k_adam(const float* __restrict__ Kb, const float* __restrict__ yc,
                                              const float* __restrict__ alpha, float* __restrict__ scal,
                                              int n, float bc1, float bc2) {
  int m = blockIdx.x, tid = threadIdx.x;
  const float* G = Kb + (size_t)m * 1048576;
  const float* y = yc + (size_t)m * NC;
  float* s = scal + m * 32;
  float cm = s[3];
  float t3=0, t4=0, t5=0, t6=0;
  for (int i = tid; i < n; i += 256) {
    float a = alpha[m*1024 + i];
    t3 += G[(size_t)i*n + i];
    t4 = fmaf(a, a, t4);
    t5 += a;
    t6 = fmaf(y[i] - cm, a, t6);
  }
  for (int off = 32; off; off >>= 1) {
    t3 += __shfl_down(t3, off); t4 += __shfl_down(t4, off);
    t5 += __shfl_down(t5, off); t6 += __shfl_down(t6, off);
  }
  __shared__ float red[4][4];
  int wid = tid >> 6, lane = tid & 63;
  if (lane == 0) { red[wid][0]=t3; red[wid][1]=t4; red[wid][2]=t5; red[wid][3]=t6; }
  __syncthreads();
  if (tid == 0) {
    t3 = red[0][0]+red[1][0]+red[2][0]+red[3][0];
    t4 = red[0][1]+red[1][1]+red[2][1]+red[3][1];
    t5 = red[0][2]+red[1][2]+red[2][2]+red[3][2];
    t6 = red[0][3]+red[1][3]+red[2][3]+red[3][3];
    float T1 = s[15], T2 = s[16];
    float ls = s[12], os = s[13], noi = s[14];
    float fn = (float)n;
    float g_ls = 0.5f / fn * (T1 - T2);
    float g_os = 0.5f / (fn * os) * (fn - noi * t3 - t6 + noi * t4);
    float g_no = 0.5f / fn * (t3 - t4);
    float g_c  = -t5 / fn;
    float gr[4];
    gr[0] = g_ls * sigmf(s[0]);
    gr[1] = g_os * sigmf(s[1]);
    gr[2] = g_no * sigmf(s[2]);
    gr[3] = g_c;
#pragma unroll
    for (int i = 0; i < 4; ++i) {
      float mv = 0.9f * s[4+i] + 0.1f * gr[i];
      float vv = 0.999f * s[8+i] + 0.001f * gr[i] * gr[i];
      s[4+i] = mv; s[8+i] = vv;
      s[i] = s[i] - 0.1f * (mv / bc1) / (sqrtf(vv / bc2) + 1e-8f);
    }
    s[12] = softplusf(s[0]);
    s[13] = softplusf(s[1]);
    s[14] = softplusf(s[2]) + 1e-4f;
  }
}

// ---------------- prediction ----------------
__global__ __launch_bounds__(256) void k_buildKtc(const float* __restrict__ xt, const float* __restrict__ xc,
                                                  float* __restrict__ Ktc, const float* __restrict__ scal) {
  int m = blockIdx.y, tid = threadIdx.x;
  int ti = blockIdx.x >> 3, tj = blockIdx.x & 7;
  __shared__ float xr[128][3], xs[128][3];
  const float* s = scal + m * 32;
  float ls = s[12], os = s[13];
  float il2 = 1.0f / (ls * ls);
  if (tid < 128) {
    int r = ti * 128 + tid;
    xr[tid][0]=xt[(size_t)m*NT*3 + r*3+0]; xr[tid][1]=xt[(size_t)m*NT*3 + r*3+1]; xr[tid][2]=xt[(size_t)m*NT*3 + r*3+2];
  } else {
    int lr = tid - 128; int r = tj * 128 + lr;
    xs[lr][0]=xc[(size_t)m*NC*3 + r*3+0]; xs[lr][1]=xc[(size_t)m*NC*3 + r*3+1]; xs[lr][2]=xc[(size_t)m*NC*3 + r*3+2];
  }
  __syncthreads();
  for (int e = tid; e < 16384; e += 256) {
    int r = e >> 7, c = e & 127;
    float d0 = xr[r][0]-xs[c][0], d1 = xr[r][1]-xs[c][1], d2 = xr[r][2]-xs[c][2];
    float r2 = d0*d0 + d1*d1 + d2*d2;
    float z = fmaxf(r2 * il2, 1e-12f);
    float dd = sqrtf(z);
    float kv = os * (1.0f + S5*dd + (5.0f/3.0f)*z) * expf(-S5*dd);
    Ktc[(size_t)m*NT*NC + (size_t)(ti*128+r)*NC + tj*128 + c] = kv;
  }
}

// W = Ktc * G   (NT x NC)
__global__ __launch_bounds__(256) void k_predW(const float* __restrict__ Ktc, const float* __restrict__ Kb,
                                               float* __restrict__ Wb) {
  int m = blockIdx.y;
  int ti = blockIdx.x >> 3, tj = blockIdx.x & 7;
  float acc[8][8] = {};
  const float* A = Ktc + (size_t)m * NT * NC + (size_t)(ti*128) * NC;
  const float* B = Kb + (size_t)m * 1048576 + tj * 128;
  mm_core<0, 0>(A, NC, B, 1024, 0, 1024, acc);
  float* C = Wb + (size_t)m * NT * NC + (size_t)(ti*128) * NC + tj * 128;
  int tx = threadIdx.x & 15, ty = threadIdx.x >> 4;
#pragma unroll
  for (int ii = 0; ii < 8; ++ii)
#pragma unroll
    for (int jj = 0; jj < 8; ++jj) C[(size_t)(ty*8+ii)*NC + tx*8+jj] = acc[ii][jj];
}

// mean/var per target
__global__ __launch_bounds__(256) void k_meanvar(const float* __restrict__ Ktc, const float* __restrict__ Wb,
                                                 const float* __restrict__ alpha, const float* __restrict__ scal,
                                                 float* __restrict__ out) {
  int t = blockIdx.x, m = blockIdx.y, tid = threadIdx.x;
  const float* kr = Ktc + (size_t)m * NT * NC + (size_t)t * NC;
  const float* wr = Wb + (size_t)m * NT * NC + (size_t)t * NC;
  const float* al = alpha + m * 1024;
  float s1 = 0.0f, s2 = 0.0f;
  for (int c = tid; c < NC; c += 256) {
    float kv = kr[c];
    s1 = fmaf(kv, al[c], s1);
    s2 = fmaf(kv, wr[c], s2);
  }
  for (int off = 32; off; off >>= 1) { s1 += __shfl_down(s1, off); s2 += __shfl_down(s2, off); }
  __shared__ float red[4][2];
  int wid = tid >> 6, lane = tid & 63;
  if (lane == 0) { red[wid][0] = s1; red[wid][1] = s2; }
  __syncthreads();
  if (tid == 0) {
    s1 = red[0][0]+red[1][0]+red[2][0]+red[3][0];
    s2 = red[0][1]+red[1][1]+red[2][1]+red[3][1];
    const float* s = scal + m * 32;
    out[(size_t)m * NT + t] = s[3] + s1;                       // mean
    out[(size_t)MM * NT + (size_t)m * NT + t] = s[13] + s[14] - s2;  // var
  }
}

// ---------------- host sequencing ----------------
static void build_G(hipStream_t stream, const float* xc, float* Kb, float* Ab, float* Tb,
                    float* scal, int n) {
  int nb = n / 128;
  k_buildK<<<dim3(nb*(nb+1)/2, MM), 256, 0, stream>>>(xc, Kb, scal, n);
  for (int k = 0; k < nb; ++k) {
    k_chol_diag<<<dim3(MM), 256, 0, stream>>>(Kb, Ab, k, n);
    if (k < nb - 1) {
      int t = nb - 1 - k;
      k_panel<<<dim3(t, MM), 256, 0, stream>>>(Kb, Ab, k, n);
      k_trail<<<dim3(t*(t+1)/2, MM), 256, 0, stream>>>(Kb, k, n);
    }
  }
  for (int s = 128; s < n; s <<= 1) {
    int st = s / 128, npair = n / (2 * s);
    k_trinvT<<<dim3(npair*st*st, MM), 256, 0, stream>>>(Kb, Ab, Tb, s, n);
    k_trinvA<<<dim3(npair*st*st, MM), 256, 0, stream>>>(Ab, Tb, s, n);
  }
  k_syrk<<<dim3(nb*(nb+1)/2, MM), 256, 0, stream>>>(Ab, Kb, n);
}

extern "C" void kernel_launch(void* const* d_in, const int* in_sizes, int n_in,
                              void* d_out, int out_size, void* d_ws, size_t ws_size,
                              hipStream_t stream) {
  const float* xc = (const float*)d_in[0];
  const float* yc = (const float*)d_in[1];
  const float* xt = (const float*)d_in[2];
  float* out = (float*)d_out;
  float* ws = (float*)d_ws;
  float* Kb    = ws;
  float* Ab    = ws + OFF_A;
  float* Tb    = ws + OFF_T;
  float* Ktc   = ws + OFF_KTC;
  float* alpha = ws + OFF_ALPHA;
  float* scal  = ws + OFF_SCAL;
  float* Wb    = Ab;  // Ab dead after syrk in final phase

  k_init<<<dim3(1), dim3(64), 0, stream>>>(scal);

  int tstep = 0;
  int chunk_ns[2] = {512, 1024};
  for (int ci = 0; ci < 2; ++ci) {
    int n = chunk_ns[ci];
    int nb = n / 128;
    for (int it = 0; it < 8; ++it) {
      ++tstep;
      float bc1 = (float)(1.0 - pow(0.9, (double)tstep));
      float bc2 = (float)(1.0 - pow(0.999, (double)tstep));
      build_G(stream, xc, Kb, Ab, Tb, scal, n);
      k_alpha<<<dim3(n/256, MM), 256, 0, stream>>>(Kb, yc, scal, alpha, n);
      k_reduce<<<dim3(nb*nb, MM), 256, 0, stream>>>(Kb, xc, alpha, scal, n);
      k_adam<<<dim3(MM), 256, 0, stream>>>(Kb, yc, alpha, scal, n, bc1, bc2);
    }
  }

  // final prediction with trained params (n = 1024)
  build_G(stream, xc, Kb, Ab, Tb, scal, 1024);
  k_alpha<<<dim3(1024/256, MM), 256, 0, stream>>>(Kb, yc, scal, alpha, 1024);
  k_buildKtc<<<dim3(4*8, MM), 256, 0, stream>>>(xt, xc, Ktc, scal);
  k_predW<<<dim3(4*8, MM), 256, 0, stream>>>(Ktc, Kb, Wb);
  k_meanvar<<<dim3(NT, MM), 256, 0, stream>>>(Ktc, Wb, alpha, scal, out);

  (void)in_sizes; (void)n_in; (void)out_size; (void)ws_size;
}